// Round 13
// baseline (778.631 us; speedup 1.0000x reference)
//
#include <hip/hip_runtime.h>
#include <math.h>

// Problem constants
#define NN      65536
#define GG      64
#define NPG     1024
#define KEIG    32
#define NBUN    64
#define BDIM    4
#define CH      256        // IN_CH == GNN_DIM == NB*BD
#define NBP     384
#define NEDGE   524288

using f16x8 = __attribute__((ext_vector_type(8))) _Float16;
using f16x4 = __attribute__((ext_vector_type(4))) _Float16;
using f32x4 = __attribute__((ext_vector_type(4))) float;

__device__ __forceinline__ float gelu_f(float x) {
    return 0.5f * x * (1.0f + erff(x * 0.70710678118654752440f));
}

// ---------------------------------------------------------------------------
// Householder Q from 6 fp16 params (BD=4: 3 reflectors)
// ---------------------------------------------------------------------------
__device__ __forceinline__ void make_Q(const _Float16* __restrict__ p, float Q[4][4])
{
#pragma unroll
    for (int i = 0; i < 4; i++)
#pragma unroll
        for (int j = 0; j < 4; j++) Q[i][j] = (i == j) ? 1.f : 0.f;
    int idx = 0;
#pragma unroll
    for (int j = 0; j < 3; j++) {
        float v[4] = {0.f, 0.f, 0.f, 0.f};
        v[j] = 1.f;
#pragma unroll
        for (int t = 0; t < 4; t++)
            if (t > j) v[t] = (float)p[idx + t - (j + 1)];
        idx += 3 - j;
        float nrm = v[0]*v[0] + v[1]*v[1] + v[2]*v[2] + v[3]*v[3];
        float s = 2.f / nrm;
#pragma unroll
        for (int i = 0; i < 4; i++) {
            float qv = Q[i][0]*v[0] + Q[i][1]*v[1] + Q[i][2]*v[2] + Q[i][3]*v[3];
            float t0 = s * qv;
#pragma unroll
            for (int c = 0; c < 4; c++) Q[i][c] -= t0 * v[c];
        }
    }
}

// ---------------------------------------------------------------------------
// fp16 MFMA GEMM (R10 core). R13 fix: the RESA residual preload was issued
// BEFORE the bias/act scatter, while acc (64 VGPR) was live -> res[8]
// (32 VGPR) spilled at budget 84 (R12 counters: WRITE 56 vs 33 logical,
// +24MB each way). Moving the preload AFTER the scatter barrier (acc dead,
// 64 regs free) makes it spill-free by construction; still 8 loads in
// flight before the store loop.
//  A32: stage A directly from fp32.  BUN==1 (dec): +vf16 = Q.x epilogue.
//  BUN==2 (lin): fp32 LDS C-tile + Q^T -> d_out direct.
// DUAL: A = concat_k(A1, A2), KTOT=512.  RESA: + A1[m,n] residual (NOUT==256).
// Outputs disjoint from ALL inputs (graph-replay safety).
// ---------------------------------------------------------------------------
template<int NOUT, int KTOT, bool DUAL, bool ACT, bool RESA, bool W16, bool A32, int BUN>
__global__ __launch_bounds__(NOUT, 3) void mgemm_k(
    const _Float16* __restrict__ A1, const _Float16* __restrict__ A2,
    const float* __restrict__ A1f, const _Float16* __restrict__ Bp,
    const float* __restrict__ bias, _Float16* __restrict__ C16,
    const float* __restrict__ xin, _Float16* __restrict__ vf16,
    const _Float16* __restrict__ nrq, float* __restrict__ outf)
{
    constexpr int NT   = KTOT / 32;     // total K-steps (8 or 16)
    constexpr int HALVES = KTOT / 256;  // 1 or 2 half-panels of K=256
    constexpr int ROWB = 512;           // LDS bytes per A row (K=256 half)
    constexpr int CPR  = 32;            // 16B chunks per A row (half)
    constexpr int TOTC = 64 * CPR;      // 2048 chunks per half-panel
    constexpr int NSTG = TOTC / NOUT;   // full stage iters per thread
    constexpr int CTS  = NOUT + 8;      // padded C-tile row stride (halfs)
    constexpr int AH   = 64 * 256;      // A half-panel halfs (32 KB)
    constexpr int W16H = W16 ? 64 * CTS : 0;
    constexpr int B2H  = (BUN == 2) ? 64 * CTS * 2 : 0;   // fp32 tile as halfs
    constexpr int LDSH = (AH > W16H) ? ((AH > B2H) ? AH : B2H)
                                     : ((W16H > B2H) ? W16H : B2H);
    __shared__ _Float16 Alds[LDSH];

    const int tid  = threadIdx.x;
    const int lane = tid & 63;
    const int wave = tid >> 6;          // wave owns cols wave*64..wave*64+63
    const int m0   = blockIdx.x * 64;   // block's 64 A rows

    const int r16 = lane & 15;          // fragment row / col within 16
    const int kc  = lane >> 4;          // k-chunk 0..3

    // B packed: chunk((wn*NT + t)*4 + q), lane-contiguous 16B each
    const _Float16* bpp = Bp + ((size_t)wave * NT * 2048) + lane * 8;

    f16x8 pa0, pa1, pa2, pa3, pb0, pb1, pb2, pb3;
    f16x8 pc0, pc1, pc2, pc3, pd0, pd1, pd2, pd3;

#define LDB(P0, P1, P2, P3, T)                                                 \
    {                                                                          \
        const _Float16* bq_ = bpp + (size_t)(T) * 2048;                        \
        P0 = *(const f16x8*)(bq_);                                             \
        P1 = *(const f16x8*)(bq_ + 512);                                       \
        P2 = *(const f16x8*)(bq_ + 1024);                                      \
        P3 = *(const f16x8*)(bq_ + 1536);                                      \
    }

    // coalesced A-chunk load (fp16 direct, or fp32 + inline cvt when A32)
    auto ldA = [&](const _Float16* B16, const float* B32, int idx) -> f16x8 {
        const size_t off = (size_t)(m0 + (idx >> 5)) * 256 + (idx & 31) * 8;
        if constexpr (A32) {
            float4 lo = *(const float4*)(B32 + off);
            float4 hi = *(const float4*)(B32 + off + 4);
            f16x8 r = { (_Float16)lo.x, (_Float16)lo.y, (_Float16)lo.z, (_Float16)lo.w,
                        (_Float16)hi.x, (_Float16)hi.y, (_Float16)hi.z, (_Float16)hi.w };
            return r;
        } else {
            return *(const f16x8*)(B16 + off);
        }
    };

    // stage one 64x256 half-panel: groups of 4 coalesced loads -> regs ->
    // swizzled LDS (16 VGPRs of staging state)
    auto stage = [&](const _Float16* B16, const float* B32) {
#pragma unroll
        for (int j0 = 0; j0 < NSTG; j0 += 4) {
            f16x8 s0, s1, s2, s3;
            const int nv = (NSTG - j0 >= 4) ? 4 : (NSTG - j0);
            int i0 = tid + (j0 + 0) * NOUT;
            int i1 = tid + (j0 + 1) * NOUT;
            int i2 = tid + (j0 + 2) * NOUT;
            int i3 = tid + (j0 + 3) * NOUT;
            if (nv > 0) s0 = ldA(B16, B32, i0);
            if (nv > 1) s1 = ldA(B16, B32, i1);
            if (nv > 2) s2 = ldA(B16, B32, i2);
            if (nv > 3) s3 = ldA(B16, B32, i3);
            if (nv > 0) *(f16x8*)((char*)Alds + ((((i0 >> 5) * ROWB + (i0 & 31) * 16)) ^ (((i0 >> 5) & 7) << 4))) = s0;
            if (nv > 1) *(f16x8*)((char*)Alds + ((((i1 >> 5) * ROWB + (i1 & 31) * 16)) ^ (((i1 >> 5) & 7) << 4))) = s1;
            if (nv > 2) *(f16x8*)((char*)Alds + ((((i2 >> 5) * ROWB + (i2 & 31) * 16)) ^ (((i2 >> 5) & 7) << 4))) = s2;
            if (nv > 3) *(f16x8*)((char*)Alds + ((((i3 >> 5) * ROWB + (i3 & 31) * 16)) ^ (((i3 >> 5) & 7) << 4))) = s3;
        }
        if (TOTC % NOUT) {              // remainder (NOUT=384 case)
            const int idx = tid + NSTG * NOUT;
            if (idx < TOTC) {
                f16x8 v = ldA(B16, B32, idx);
                const int r = idx >> 5, c = idx & 31;
                *(f16x8*)((char*)Alds + ((r * ROWB + c * 16) ^ ((r & 7) << 4))) = v;
            }
        }
    };

    // issue B prefetch for steps 0..3 BEFORE staging (overlaps A latency)
    LDB(pa0, pa1, pa2, pa3, 0)
    LDB(pb0, pb1, pb2, pb3, 1)
    LDB(pc0, pc1, pc2, pc3, 2)
    LDB(pd0, pd1, pd2, pd3, 3)

    stage(A1, A1f);
    __syncthreads();

    f32x4 acc[4][4];
#pragma unroll
    for (int i = 0; i < 4; i++)
#pragma unroll
        for (int j = 0; j < 4; j++) acc[i][j] = 0.f;

#define MSTEP(OFF, P0, P1, P2, P3)                                             \
    {                                                                          \
        const char* ap_ = (const char*)Alds + (OFF);                           \
        f16x8 a0_ = *(const f16x8*)(ap_);                                      \
        f16x8 a1_ = *(const f16x8*)(ap_ + 16 * ROWB);                          \
        f16x8 a2_ = *(const f16x8*)(ap_ + 32 * ROWB);                          \
        f16x8 a3_ = *(const f16x8*)(ap_ + 48 * ROWB);                          \
        acc[0][0] = __builtin_amdgcn_mfma_f32_16x16x32_f16(a0_, P0, acc[0][0], 0, 0, 0); \
        acc[0][1] = __builtin_amdgcn_mfma_f32_16x16x32_f16(a0_, P1, acc[0][1], 0, 0, 0); \
        acc[0][2] = __builtin_amdgcn_mfma_f32_16x16x32_f16(a0_, P2, acc[0][2], 0, 0, 0); \
        acc[0][3] = __builtin_amdgcn_mfma_f32_16x16x32_f16(a0_, P3, acc[0][3], 0, 0, 0); \
        acc[1][0] = __builtin_amdgcn_mfma_f32_16x16x32_f16(a1_, P0, acc[1][0], 0, 0, 0); \
        acc[1][1] = __builtin_amdgcn_mfma_f32_16x16x32_f16(a1_, P1, acc[1][1], 0, 0, 0); \
        acc[1][2] = __builtin_amdgcn_mfma_f32_16x16x32_f16(a1_, P2, acc[1][2], 0, 0, 0); \
        acc[1][3] = __builtin_amdgcn_mfma_f32_16x16x32_f16(a1_, P3, acc[1][3], 0, 0, 0); \
        acc[2][0] = __builtin_amdgcn_mfma_f32_16x16x32_f16(a2_, P0, acc[2][0], 0, 0, 0); \
        acc[2][1] = __builtin_amdgcn_mfma_f32_16x16x32_f16(a2_, P1, acc[2][1], 0, 0, 0); \
        acc[2][2] = __builtin_amdgcn_mfma_f32_16x16x32_f16(a2_, P2, acc[2][2], 0, 0, 0); \
        acc[2][3] = __builtin_amdgcn_mfma_f32_16x16x32_f16(a2_, P3, acc[2][3], 0, 0, 0); \
        acc[3][0] = __builtin_amdgcn_mfma_f32_16x16x32_f16(a3_, P0, acc[3][0], 0, 0, 0); \
        acc[3][1] = __builtin_amdgcn_mfma_f32_16x16x32_f16(a3_, P1, acc[3][1], 0, 0, 0); \
        acc[3][2] = __builtin_amdgcn_mfma_f32_16x16x32_f16(a3_, P2, acc[3][2], 0, 0, 0); \
        acc[3][3] = __builtin_amdgcn_mfma_f32_16x16x32_f16(a3_, P3, acc[3][3], 0, 0, 0); \
    }

    const int swz = (r16 & 7) << 4;
#pragma unroll
    for (int h = 0; h < HALVES; ++h) {
        if (h > 0) {
            __syncthreads();            // all waves done reading half 0
            stage(A2, nullptr);
            __syncthreads();
            // refill B queue AFTER the restage: no B regs live across it
            LDB(pa0, pa1, pa2, pa3, 8)
            LDB(pb0, pb1, pb2, pb3, 9)
            LDB(pc0, pc1, pc2, pc3, 10)
            LDB(pd0, pd1, pd2, pd3, 11)
        }
        int au = r16 * ROWB + kc * 16;
#pragma unroll
        for (int tt = 0; tt < 8; tt += 4) {
            const int t = h * 8 + tt;   // global K-step for B indexing
            MSTEP((au      ) ^ swz, pa0, pa1, pa2, pa3)
            if (tt + 4 < 8) LDB(pa0, pa1, pa2, pa3, t + 4)
            MSTEP((au +  64) ^ swz, pb0, pb1, pb2, pb3)
            if (tt + 5 < 8) LDB(pb0, pb1, pb2, pb3, t + 5)
            MSTEP((au + 128) ^ swz, pc0, pc1, pc2, pc3)
            if (tt + 6 < 8) LDB(pc0, pc1, pc2, pc3, t + 6)
            MSTEP((au + 192) ^ swz, pd0, pd1, pd2, pd3)
            if (tt + 7 < 8) LDB(pd0, pd1, pd2, pd3, t + 7)
            au += 256;
        }
    }
#undef LDB
#undef MSTEP

    // epilogue: C[m = quad*4+reg][n = lane&15] per 16x16 tile (m89 layout)
    const int rbase = (lane >> 4) * 4;
    const int ncol  = lane & 15;
    if constexpr (BUN == 2) {
        // fp32 LDS C-tile -> per-(row,bundle) Q^T transform -> d_out direct
        __syncthreads();                // all waves done reading Alds
        float* Cl = (float*)Alds;
        constexpr int CS4 = NOUT + 8;
#pragma unroll
        for (int nt = 0; nt < 4; nt++) {
            const int n = wave * 64 + nt * 16 + ncol;
            const float bs = bias[n];
#pragma unroll
            for (int mt = 0; mt < 4; mt++)
#pragma unroll
                for (int i = 0; i < 4; i++)
                    Cl[(mt * 16 + rbase + i) * CS4 + n] = acc[mt][nt][i] + bs;
        }
        __syncthreads();
#pragma unroll
        for (int it = 0; it < 4096 / NOUT; it++) {
            const int item = tid + it * NOUT;
            const int row = item >> 6, b = item & 63;
            float4 v = *(const float4*)&Cl[row * CS4 + b * 4];
            float Q[4][4];
            make_Q(nrq + (size_t)(m0 + row) * 384 + b * 6, Q);
            float4 o;
            o.x = Q[0][0]*v.x + Q[1][0]*v.y + Q[2][0]*v.z + Q[3][0]*v.w;
            o.y = Q[0][1]*v.x + Q[1][1]*v.y + Q[2][1]*v.z + Q[3][1]*v.w;
            o.z = Q[0][2]*v.x + Q[1][2]*v.y + Q[2][2]*v.z + Q[3][2]*v.w;
            o.w = Q[0][3]*v.x + Q[1][3]*v.y + Q[2][3]*v.z + Q[3][3]*v.w;
            *(float4*)(outf + (size_t)(m0 + row) * 256 + b * 4) = o;
        }
    } else {
        // W16: coalesced path via padded fp16 LDS C-tile
        __syncthreads();                // all waves done reading Alds
        constexpr int CPRN = NOUT / 8;  // 16B chunks per C row
        constexpr int CPT  = 64 * CPRN / NOUT;   // chunks per thread (= 8)
        // scatter bias+act into padded LDS C-tile (acc fully consumed here)
#pragma unroll
        for (int nt = 0; nt < 4; nt++) {
            const int n = wave * 64 + nt * 16 + ncol;
            const float bs = bias[n];
#pragma unroll
            for (int mt = 0; mt < 4; mt++) {
#pragma unroll
                for (int i = 0; i < 4; i++) {
                    const int mr = mt * 16 + rbase + i;
                    float v = acc[mt][nt][i] + bs;
                    if (ACT) v = gelu_f(v);
                    Alds[mr * CTS + n] = (_Float16)v;
                }
            }
        }
        __syncthreads();
        // R13: residual preload AFTER the scatter barrier (acc dead -> 64
        // regs free -> res[8] lives in registers, no scratch spill)
        f16x8 res[CPT];
        if constexpr (RESA) {
#pragma unroll
            for (int k2 = 0; k2 < CPT; k2++) {
                const int c = tid + k2 * NOUT;
                const int row = c / CPRN, col = c - row * CPRN;
                res[k2] = *(const f16x8*)(A1 + (size_t)(m0 + row) * 256 + col * 8);
            }
        }
#pragma unroll
        for (int k2 = 0; k2 < CPT; k2++) {
            const int c = tid + k2 * NOUT;
            const int row = c / CPRN, col = c - row * CPRN;
            f16x8 v = *(const f16x8*)&Alds[row * CTS + col * 8];
            if constexpr (RESA) v = v + res[k2];
            *(f16x8*)(C16 + (size_t)(m0 + row) * NOUT + col * 8) = v;
        }
        if constexpr (BUN == 1) {
            // fused bundle<false>: vf16[n, b*4+i] = sum_j Q[i][j] x[n, b*4+j]
            constexpr int NIT = (4096 + NOUT - 1) / NOUT;
#pragma unroll
            for (int it = 0; it < NIT; it++) {
                const int item = tid + it * NOUT;
                if (item < 4096) {
                    const int row = item >> 6, b = item & 63;
                    float4 xv = *(const float4*)(xin + (size_t)(m0 + row) * 256 + b * 4);
                    float Q[4][4];
                    make_Q(&Alds[row * CTS + b * 6], Q);
                    f16x4 o = {
                        (_Float16)(Q[0][0]*xv.x + Q[0][1]*xv.y + Q[0][2]*xv.z + Q[0][3]*xv.w),
                        (_Float16)(Q[1][0]*xv.x + Q[1][1]*xv.y + Q[1][2]*xv.z + Q[1][3]*xv.w),
                        (_Float16)(Q[2][0]*xv.x + Q[2][1]*xv.y + Q[2][2]*xv.z + Q[2][3]*xv.w),
                        (_Float16)(Q[3][0]*xv.x + Q[3][1]*xv.y + Q[3][2]*xv.z + Q[3][3]*xv.w) };
                    *(f16x4*)(vf16 + (size_t)(m0 + row) * 256 + b * 4) = o;
                }
            }
        }
    }
}

// ---------------------------------------------------------------------------
// Merged prep kernel: 5 weight packs + bias combine + deg zero in ONE launch.
// ---------------------------------------------------------------------------
__device__ __forceinline__ void pack_body(
    const float* __restrict__ W1, const float* __restrict__ W2,
    _Float16* __restrict__ Bp, int cid, int NOUT, int lognt)
{
    const int NT = 1 << lognt;
    const int l  = cid & 63;
    const int q  = (cid >> 6) & 3;
    const int c2 = cid >> 8;            // wn*NT + t
    const int t  = c2 & (NT - 1);
    const int wn = c2 >> lognt;
    const int n  = wn * 64 + q * 16 + (l & 15);
    const int k0 = t * 32 + (l >> 4) * 8;
    f16x8 v;
#pragma unroll
    for (int j = 0; j < 8; j++) {
        const int k = k0 + j;
        float w = (W2 && k >= 256) ? W2[(size_t)(k - 256) * NOUT + n]
                                   : W1[(size_t)k * NOUT + n];
        v[j] = (_Float16)w;
    }
    *(f16x8*)(Bp + (size_t)cid * 8) = v;
}

__global__ __launch_bounds__(256) void packall_k(
    const float* __restrict__ enc_w, const float* __restrict__ self_w,
    const float* __restrict__ nb_w, const float* __restrict__ dec_w,
    const float* __restrict__ lin_w, const float* __restrict__ self_b,
    const float* __restrict__ nb_b,
    _Float16* __restrict__ enc16, _Float16* __restrict__ l1w,
    _Float16* __restrict__ l2w, _Float16* __restrict__ dec16,
    _Float16* __restrict__ lin16, float* __restrict__ lbias,
    float* __restrict__ degf)
{
    const int b = blockIdx.x;
    const int tid = threadIdx.x;
    if (b < 32) {
        pack_body(enc_w, nullptr, enc16, b * 256 + tid, 256, 3);
    } else if (b < 96) {
        pack_body(self_w, nb_w, l1w, (b - 32) * 256 + tid, 256, 4);
    } else if (b < 160) {
        pack_body(self_w + 65536, nb_w + 65536, l2w, (b - 96) * 256 + tid, 256, 4);
    } else if (b < 208) {
        pack_body(dec_w, nullptr, dec16, (b - 160) * 256 + tid, 384, 3);
    } else if (b < 240) {
        pack_body(lin_w, nullptr, lin16, (b - 208) * 256 + tid, 256, 3);
    } else if (b == 240) {
        for (int i = tid; i < 512; i += 256) lbias[i] = self_b[i] + nb_b[i];
    } else {
        // zero deg: 65536 ints = 16384 float4s
        const int j = (b - 241) * 256 + tid;
        ((float4*)degf)[j] = make_float4(0.f, 0.f, 0.f, 0.f);
    }
}

// ---------------------------------------------------------------------------
// CSR build: histogram of dst, exclusive scan, cursor fill
// ---------------------------------------------------------------------------
__global__ __launch_bounds__(256) void hist_k(const int* __restrict__ ei, int* __restrict__ deg)
{
    int e = blockIdx.x * 256 + threadIdx.x;
    if (e < NEDGE) atomicAdd(&deg[ei[NEDGE + e]], 1);
}

__global__ __launch_bounds__(1024) void scan_k(
    const int* __restrict__ deg, int* __restrict__ off, int* __restrict__ cursor)
{
    __shared__ int sh[1024];
    const int tid = threadIdx.x;
    const int base = tid * 64;
    int s = 0;
#pragma unroll 8
    for (int i = 0; i < 64; i++) s += deg[base + i];
    const int mysum = s;
    sh[tid] = s;
    __syncthreads();
    for (int ofs = 1; ofs < 1024; ofs <<= 1) {
        int v = (tid >= ofs) ? sh[tid - ofs] : 0;
        __syncthreads();
        sh[tid] += v;
        __syncthreads();
    }
    int running = sh[tid] - mysum;
    for (int i = 0; i < 64; i++) {
        off[base + i] = running;
        cursor[base + i] = running;
        running += deg[base + i];
    }
    if (tid == 1023) off[NN] = running;
}

__global__ __launch_bounds__(256) void fill_k(
    const int* __restrict__ ei, int* __restrict__ cursor, int* __restrict__ csr)
{
    int e = blockIdx.x * 256 + threadIdx.x;
    if (e < NEDGE) {
        int d = ei[NEDGE + e];
        int pos = atomicAdd(&cursor[d], 1);
        csr[pos] = ei[e];   // src
    }
}

// ---------------------------------------------------------------------------
// Gather segment-sum over fp16 h: fp32 accum, fp16 out.
// R13: 2 nodes per wave, 32 lanes x f16x8 per row (1KB/load-instruction,
// half the instruction count of the 64-lane f16x4 version). Common-min
// main loop (no divergence), short divergent tail per half.
// Block = 4 waves = 8 nodes; grid NN/8.
// ---------------------------------------------------------------------------
__global__ __launch_bounds__(256) void gather16_k(
    const _Float16* __restrict__ h, const int* __restrict__ off,
    const int* __restrict__ csr, _Float16* __restrict__ agg)
{
    const int w    = threadIdx.x >> 6;
    const int lane = threadIdx.x & 63;
    const int half = lane >> 5;         // 0/1: which node of the pair
    const int li   = lane & 31;         // lane within node (8 channels each)
    const int n    = blockIdx.x * 8 + w * 2 + half;
    const int s0 = off[n], s1 = off[n + 1];
    const int deg = s1 - s0;
    const int odeg = __shfl(deg, lane ^ 32);   // other half's degree
    const int cm = deg < odeg ? deg : odeg;    // common (wave-uniform) count

    float a0 = 0.f, a1 = 0.f, a2 = 0.f, a3 = 0.f;
    float a4 = 0.f, a5 = 0.f, a6 = 0.f, a7 = 0.f;

#define GACC(V) { a0 += (float)V[0]; a1 += (float)V[1]; a2 += (float)V[2]; \
                  a3 += (float)V[3]; a4 += (float)V[4]; a5 += (float)V[5]; \
                  a6 += (float)V[6]; a7 += (float)V[7]; }

    int j = 0;
    for (; j + 3 < cm; j += 4) {
        const int i0 = csr[s0 + j],     i1 = csr[s0 + j + 1];
        const int i2 = csr[s0 + j + 2], i3 = csr[s0 + j + 3];
        f16x8 v0 = ((const f16x8*)(h + (size_t)i0 * CH))[li];
        f16x8 v1 = ((const f16x8*)(h + (size_t)i1 * CH))[li];
        f16x8 v2 = ((const f16x8*)(h + (size_t)i2 * CH))[li];
        f16x8 v3 = ((const f16x8*)(h + (size_t)i3 * CH))[li];
        GACC(v0) GACC(v1) GACC(v2) GACC(v3)
    }
    for (; j < cm; j++) {
        f16x8 v = ((const f16x8*)(h + (size_t)csr[s0 + j] * CH))[li];
        GACC(v)
    }
    for (; j < deg; j++) {              // divergent tail (one half active)
        f16x8 v = ((const f16x8*)(h + (size_t)csr[s0 + j] * CH))[li];
        GACC(v)
    }
#undef GACC

    f16x8 o = { (_Float16)a0, (_Float16)a1, (_Float16)a2, (_Float16)a3,
                (_Float16)a4, (_Float16)a5, (_Float16)a6, (_Float16)a7 };
    ((f16x8*)(agg + (size_t)n * CH))[li] = o;
}

// ---------------------------------------------------------------------------
// Spectral kernels (vf is fp16). spec_proj: atomic-free private partials;
// hsum: 8-way reduce (16 MB -> 2 MB); spec_reproj: reads reduced hs.
// ---------------------------------------------------------------------------
__global__ __launch_bounds__(256) void spec_proj_k(
    const _Float16* __restrict__ v, const float* __restrict__ eigvec,
    float* __restrict__ hs8)
{
    const int g = blockIdx.x;
    const int yb = blockIdx.y;
    const int nbase = g * NPG + yb * 128;
    __shared__ float evs[16][32];
    float acc[32];
#pragma unroll
    for (int k = 0; k < 32; k++) acc[k] = 0.f;
    for (int nt = 0; nt < 128; nt += 16) {
        __syncthreads();
        for (int i = threadIdx.x; i < 512; i += 256) {
            int nn = i >> 5, kk = i & 31;
            evs[nn][kk] = eigvec[(size_t)(nbase + nt + nn) * KEIG + kk];
        }
        __syncthreads();
#pragma unroll 4
        for (int nn = 0; nn < 16; nn++) {
            float hv = (float)v[(size_t)(nbase + nt + nn) * CH + threadIdx.x];
#pragma unroll
            for (int k = 0; k < 32; k++) acc[k] += evs[nn][k] * hv;
        }
    }
    float* o = hs8 + (((size_t)g * 8 + yb) * KEIG) * CH + threadIdx.x;
#pragma unroll
    for (int k = 0; k < 32; k++) o[k * CH] = acc[k];
}

__global__ __launch_bounds__(256) void hsum_k(
    const float* __restrict__ hs8, float* __restrict__ hs)
{
    const size_t i = (size_t)blockIdx.x * 256 + threadIdx.x;  // over 64*32*256
    const int g = (int)(i >> 13);            // i / 8192
    const size_t r = i & 8191;
    const float* p = hs8 + (size_t)g * 8 * 8192 + r;
    float s = ((p[0] + p[8192]) + (p[2 * 8192] + p[3 * 8192]))
            + ((p[4 * 8192] + p[5 * 8192]) + (p[6 * 8192] + p[7 * 8192]));
    hs[i] = s;
}

// out16[g,n,d] = sum_v ev[g,n,v] * hs[g,v,d] * exp(-eigval[g,v]*taus[d>>2])
__global__ __launch_bounds__(256) void spec_reproj16_k(
    const float* __restrict__ eigvec, const float* __restrict__ hs,
    const float* __restrict__ eigval, const float* __restrict__ taus,
    _Float16* __restrict__ out16)
{
    const int g = blockIdx.x >> 4;
    const int nbase = g * NPG + (blockIdx.x & 15) * 64;
    const float tau = taus[threadIdx.x >> 2];
    float hsr[32];
    const float* hg = hs + (size_t)g * KEIG * CH + threadIdx.x;
#pragma unroll
    for (int k = 0; k < 32; k++)
        hsr[k] = hg[k * CH] * expf(-eigval[g * KEIG + k] * tau);
    __shared__ float evs[64][32];
    for (int i = threadIdx.x; i < 2048; i += 256) {
        int nn = i >> 5, kk = i & 31;
        evs[nn][kk] = eigvec[(size_t)(nbase + nn) * KEIG + kk];
    }
    __syncthreads();
    for (int nn = 0; nn < 64; nn++) {
        float a = 0.f;
#pragma unroll
        for (int k = 0; k < 32; k++) a += evs[nn][k] * hsr[k];
        out16[(size_t)(nbase + nn) * CH + threadIdx.x] = (_Float16)a;
    }
}

// ---------------------------------------------------------------------------
extern "C" void kernel_launch(void* const* d_in, const int* in_sizes, int n_in,
                              void* d_out, int out_size, void* d_ws, size_t ws_size,
                              hipStream_t stream)
{
    const float* x      = (const float*)d_in[0];
    const float* eigvec = (const float*)d_in[1];
    const float* eigval = (const float*)d_in[2];
    const float* taus   = (const float*)d_in[3];
    const float* enc_w  = (const float*)d_in[4];
    const float* enc_b  = (const float*)d_in[5];
    const float* self_w = (const float*)d_in[6];
    const float* self_b = (const float*)d_in[7];
    const float* nb_w   = (const float*)d_in[8];
    const float* nb_b   = (const float*)d_in[9];
    const float* dec_w  = (const float*)d_in[10];
    const float* dec_b  = (const float*)d_in[11];
    const float* lin_w  = (const float*)d_in[12];
    const float* lin_b  = (const float*)d_in[13];
    const int*   ei     = (const int*)d_in[14];
    (void)in_sizes; (void)n_in; (void)out_size; (void)ws_size;

    float* ws = (float*)d_ws;
    // Stream-ordered lifetimes (float-slot offsets):
    //  [0,        4194304)  hs8 [64,8,32,256] fp32 partials (16 MB)
    //  [4194304,  4718592)  hs  [64,32,256] fp32 reduced (2 MB)
    //  [8388608, 16777216)  h0
    //  [16777216,25165824)  h1 -> vf16 [NN,256] fp16 (h1 dead after L2)
    //  [25165824,33554432)  agg          -> nr16 part
    //  [33554432,34275329)  CSR ints     -> nr16 part
    //  [25165824,37748736)  nr16 [NN,384] fp16 (dec out; agg+CSR dead)
    //  [37748752,37995024)  packed weights + lbias
    //  [37995024,46383632)  h2 [NN,256] fp16
    // high-water: 46,383,632 fl = 185.5 MB
    _Float16* h0  = (_Float16*)(ws + 8388608);
    _Float16* h1  = (_Float16*)(ws + 16777216);
    _Float16* agg = (_Float16*)(ws + 25165824);
    int* ibase  = (int*)(ws + 33554432);
    int* deg    = ibase;                 // NN
    int* off    = ibase + 65536;         // NN+1
    int* cursor = ibase + 131073;        // NN
    int* csr    = ibase + 196609;        // NEDGE (ends slot 34275329)
    _Float16* nr16 = (_Float16*)(ws + 25165824);  // [NN,384] fp16
    float* wb = ws + 37748752;
    _Float16* enc16 = (_Float16*)(wb);            // packed [256x256]
    _Float16* l1w   = (_Float16*)(wb + 32768);    // packed [256x512]
    _Float16* l2w   = (_Float16*)(wb + 98304);    // packed [256x512]
    _Float16* dec16 = (_Float16*)(wb + 163840);   // packed [384x256]
    _Float16* lin16 = (_Float16*)(wb + 212992);   // packed [256x256]
    float* lbias = wb + 245760;                   // [2,256] (ends wb+246272)
    _Float16* h2 = (_Float16*)(ws + 37995024);    // [NN,256] fp16
    _Float16* vf16 = (_Float16*)(ws + 16777216);  // [NN,256] fp16 (h1 dead)
    float* hs8 = ws;                              // [64,8,32,256] fp32
    float* hs  = ws + 4194304;                    // [64,32,256] fp32

    dim3 blk(256);

    // ---- prep: packs + bias + deg zero in ONE launch ----
    packall_k<<<305, blk, 0, stream>>>(enc_w, self_w, nb_w, dec_w, lin_w,
        self_b, nb_b, enc16, l1w, l2w, dec16, lin16, lbias, (float*)deg);
    hist_k<<<NEDGE / 256, blk, 0, stream>>>(ei, deg);
    scan_k<<<1, 1024, 0, stream>>>(deg, off, cursor);
    fill_k<<<NEDGE / 256, blk, 0, stream>>>(ei, cursor, csr);

    // ---- h0 = gelu(x @ enc_w + enc_b)  (A32: stages fp32 x directly) ----
    mgemm_k<256, 256, false, true, false, true, true, 0><<<1024, blk, 0, stream>>>(
        nullptr, nullptr, x, enc16, enc_b, h0, nullptr, nullptr, nullptr, nullptr);

    // ---- GNN layer 1: h1 = gelu([h0,agg]@W + b) + h0 ----
    gather16_k<<<NN / 8, blk, 0, stream>>>(h0, off, csr, agg);
    mgemm_k<256, 512, true, true, true, true, false, 0><<<1024, blk, 0, stream>>>(
        h0, agg, nullptr, l1w, lbias, h1, nullptr, nullptr, nullptr, nullptr);

    // ---- GNN layer 2: h0 = gelu([h1,agg]@W + b) + h1 ----
    gather16_k<<<NN / 8, blk, 0, stream>>>(h1, off, csr, agg);
    mgemm_k<256, 512, true, true, true, true, false, 0><<<1024, blk, 0, stream>>>(
        h1, agg, nullptr, l2w, lbias + 256, h0, nullptr, nullptr, nullptr, nullptr);

    // ---- node_rep = h0 @ dec_w + dec_b  + FUSED vf16 = Q . x ----
    mgemm_k<384, 256, false, false, false, true, false, 1><<<1024, dim3(384), 0, stream>>>(
        h0, nullptr, nullptr, dec16, dec_b, nr16, x, vf16, nullptr, nullptr);

    // ---- spectral filter (atomic-free partials + tiny reduce) ----
    spec_proj_k<<<dim3(GG, 8), blk, 0, stream>>>(vf16, eigvec, hs8);
    hsum_k<<<2048, blk, 0, stream>>>(hs8, hs);
    spec_reproj16_k<<<GG * 16, blk, 0, stream>>>(eigvec, hs, eigval, taus, h2);

    // ---- out = Q^T . (h2 @ lin_w + lin_b)  (FUSED, fp32 tile, direct) ----
    mgemm_k<256, 256, false, false, false, false, false, 2><<<1024, blk, 0, stream>>>(
        h2, nullptr, nullptr, lin16, lin_b, nullptr, nullptr, nullptr, nr16, (float*)d_out);
}

// Round 14
// 622.463 us; speedup vs baseline: 1.2509x; 1.2509x over previous
//
#include <hip/hip_runtime.h>
#include <math.h>

// Problem constants
#define NN      65536
#define GG      64
#define NPG     1024
#define KEIG    32
#define NBUN    64
#define BDIM    4
#define CH      256        // IN_CH == GNN_DIM == NB*BD
#define NBP     384
#define NEDGE   524288

using f16x8 = __attribute__((ext_vector_type(8))) _Float16;
using f16x4 = __attribute__((ext_vector_type(4))) _Float16;
using f32x4 = __attribute__((ext_vector_type(4))) float;

__device__ __forceinline__ float gelu_f(float x) {
    return 0.5f * x * (1.0f + erff(x * 0.70710678118654752440f));
}

// ---------------------------------------------------------------------------
// Householder Q from 6 fp16 params (BD=4: 3 reflectors)
// ---------------------------------------------------------------------------
__device__ __forceinline__ void make_Q(const _Float16* __restrict__ p, float Q[4][4])
{
#pragma unroll
    for (int i = 0; i < 4; i++)
#pragma unroll
        for (int j = 0; j < 4; j++) Q[i][j] = (i == j) ? 1.f : 0.f;
    int idx = 0;
#pragma unroll
    for (int j = 0; j < 3; j++) {
        float v[4] = {0.f, 0.f, 0.f, 0.f};
        v[j] = 1.f;
#pragma unroll
        for (int t = 0; t < 4; t++)
            if (t > j) v[t] = (float)p[idx + t - (j + 1)];
        idx += 3 - j;
        float nrm = v[0]*v[0] + v[1]*v[1] + v[2]*v[2] + v[3]*v[3];
        float s = 2.f / nrm;
#pragma unroll
        for (int i = 0; i < 4; i++) {
            float qv = Q[i][0]*v[0] + Q[i][1]*v[1] + Q[i][2]*v[2] + Q[i][3]*v[3];
            float t0 = s * qv;
#pragma unroll
            for (int c = 0; c < 4; c++) Q[i][c] -= t0 * v[c];
        }
    }
}

// ---------------------------------------------------------------------------
// fp16 MFMA GEMM — FROZEN at R12 (best measured: 622us total, DUAL ~60us).
// R13's "spill fix" (res preload after scatter barrier) REGRESSED the whole
// kernel 60->108us (2x BW collapse; compiler schedule degraded) and WRITE
// only dropped 6MB -> the ~20MB spill was never res[]. Reverted verbatim.
// DO NOT reorder the epilogue residual preload.
//  A32: stage A directly from fp32.  BUN==1 (dec): +vf16 = Q.x epilogue.
//  BUN==2 (lin): fp32 LDS C-tile + Q^T -> d_out direct.
// DUAL: A = concat_k(A1, A2), KTOT=512.  RESA: + A1[m,n] residual (NOUT==256).
// Outputs disjoint from ALL inputs (graph-replay safety).
// ---------------------------------------------------------------------------
template<int NOUT, int KTOT, bool DUAL, bool ACT, bool RESA, bool W16, bool A32, int BUN>
__global__ __launch_bounds__(NOUT, 3) void mgemm_k(
    const _Float16* __restrict__ A1, const _Float16* __restrict__ A2,
    const float* __restrict__ A1f, const _Float16* __restrict__ Bp,
    const float* __restrict__ bias, _Float16* __restrict__ C16,
    const float* __restrict__ xin, _Float16* __restrict__ vf16,
    const _Float16* __restrict__ nrq, float* __restrict__ outf)
{
    constexpr int NT   = KTOT / 32;     // total K-steps (8 or 16)
    constexpr int HALVES = KTOT / 256;  // 1 or 2 half-panels of K=256
    constexpr int ROWB = 512;           // LDS bytes per A row (K=256 half)
    constexpr int CPR  = 32;            // 16B chunks per A row (half)
    constexpr int TOTC = 64 * CPR;      // 2048 chunks per half-panel
    constexpr int NSTG = TOTC / NOUT;   // full stage iters per thread
    constexpr int CTS  = NOUT + 8;      // padded C-tile row stride (halfs)
    constexpr int AH   = 64 * 256;      // A half-panel halfs (32 KB)
    constexpr int W16H = W16 ? 64 * CTS : 0;
    constexpr int B2H  = (BUN == 2) ? 64 * CTS * 2 : 0;   // fp32 tile as halfs
    constexpr int LDSH = (AH > W16H) ? ((AH > B2H) ? AH : B2H)
                                     : ((W16H > B2H) ? W16H : B2H);
    __shared__ _Float16 Alds[LDSH];

    const int tid  = threadIdx.x;
    const int lane = tid & 63;
    const int wave = tid >> 6;          // wave owns cols wave*64..wave*64+63
    const int m0   = blockIdx.x * 64;   // block's 64 A rows

    const int r16 = lane & 15;          // fragment row / col within 16
    const int kc  = lane >> 4;          // k-chunk 0..3

    // B packed: chunk((wn*NT + t)*4 + q), lane-contiguous 16B each
    const _Float16* bpp = Bp + ((size_t)wave * NT * 2048) + lane * 8;

    f16x8 pa0, pa1, pa2, pa3, pb0, pb1, pb2, pb3;
    f16x8 pc0, pc1, pc2, pc3, pd0, pd1, pd2, pd3;

#define LDB(P0, P1, P2, P3, T)                                                 \
    {                                                                          \
        const _Float16* bq_ = bpp + (size_t)(T) * 2048;                        \
        P0 = *(const f16x8*)(bq_);                                             \
        P1 = *(const f16x8*)(bq_ + 512);                                       \
        P2 = *(const f16x8*)(bq_ + 1024);                                      \
        P3 = *(const f16x8*)(bq_ + 1536);                                      \
    }

    // coalesced A-chunk load (fp16 direct, or fp32 + inline cvt when A32)
    auto ldA = [&](const _Float16* B16, const float* B32, int idx) -> f16x8 {
        const size_t off = (size_t)(m0 + (idx >> 5)) * 256 + (idx & 31) * 8;
        if constexpr (A32) {
            float4 lo = *(const float4*)(B32 + off);
            float4 hi = *(const float4*)(B32 + off + 4);
            f16x8 r = { (_Float16)lo.x, (_Float16)lo.y, (_Float16)lo.z, (_Float16)lo.w,
                        (_Float16)hi.x, (_Float16)hi.y, (_Float16)hi.z, (_Float16)hi.w };
            return r;
        } else {
            return *(const f16x8*)(B16 + off);
        }
    };

    // stage one 64x256 half-panel: groups of 4 coalesced loads -> regs ->
    // swizzled LDS (16 VGPRs of staging state)
    auto stage = [&](const _Float16* B16, const float* B32) {
#pragma unroll
        for (int j0 = 0; j0 < NSTG; j0 += 4) {
            f16x8 s0, s1, s2, s3;
            const int nv = (NSTG - j0 >= 4) ? 4 : (NSTG - j0);
            int i0 = tid + (j0 + 0) * NOUT;
            int i1 = tid + (j0 + 1) * NOUT;
            int i2 = tid + (j0 + 2) * NOUT;
            int i3 = tid + (j0 + 3) * NOUT;
            if (nv > 0) s0 = ldA(B16, B32, i0);
            if (nv > 1) s1 = ldA(B16, B32, i1);
            if (nv > 2) s2 = ldA(B16, B32, i2);
            if (nv > 3) s3 = ldA(B16, B32, i3);
            if (nv > 0) *(f16x8*)((char*)Alds + ((((i0 >> 5) * ROWB + (i0 & 31) * 16)) ^ (((i0 >> 5) & 7) << 4))) = s0;
            if (nv > 1) *(f16x8*)((char*)Alds + ((((i1 >> 5) * ROWB + (i1 & 31) * 16)) ^ (((i1 >> 5) & 7) << 4))) = s1;
            if (nv > 2) *(f16x8*)((char*)Alds + ((((i2 >> 5) * ROWB + (i2 & 31) * 16)) ^ (((i2 >> 5) & 7) << 4))) = s2;
            if (nv > 3) *(f16x8*)((char*)Alds + ((((i3 >> 5) * ROWB + (i3 & 31) * 16)) ^ (((i3 >> 5) & 7) << 4))) = s3;
        }
        if (TOTC % NOUT) {              // remainder (NOUT=384 case)
            const int idx = tid + NSTG * NOUT;
            if (idx < TOTC) {
                f16x8 v = ldA(B16, B32, idx);
                const int r = idx >> 5, c = idx & 31;
                *(f16x8*)((char*)Alds + ((r * ROWB + c * 16) ^ ((r & 7) << 4))) = v;
            }
        }
    };

    // issue B prefetch for steps 0..3 BEFORE staging (overlaps A latency)
    LDB(pa0, pa1, pa2, pa3, 0)
    LDB(pb0, pb1, pb2, pb3, 1)
    LDB(pc0, pc1, pc2, pc3, 2)
    LDB(pd0, pd1, pd2, pd3, 3)

    stage(A1, A1f);
    __syncthreads();

    f32x4 acc[4][4];
#pragma unroll
    for (int i = 0; i < 4; i++)
#pragma unroll
        for (int j = 0; j < 4; j++) acc[i][j] = 0.f;

#define MSTEP(OFF, P0, P1, P2, P3)                                             \
    {                                                                          \
        const char* ap_ = (const char*)Alds + (OFF);                           \
        f16x8 a0_ = *(const f16x8*)(ap_);                                      \
        f16x8 a1_ = *(const f16x8*)(ap_ + 16 * ROWB);                          \
        f16x8 a2_ = *(const f16x8*)(ap_ + 32 * ROWB);                          \
        f16x8 a3_ = *(const f16x8*)(ap_ + 48 * ROWB);                          \
        acc[0][0] = __builtin_amdgcn_mfma_f32_16x16x32_f16(a0_, P0, acc[0][0], 0, 0, 0); \
        acc[0][1] = __builtin_amdgcn_mfma_f32_16x16x32_f16(a0_, P1, acc[0][1], 0, 0, 0); \
        acc[0][2] = __builtin_amdgcn_mfma_f32_16x16x32_f16(a0_, P2, acc[0][2], 0, 0, 0); \
        acc[0][3] = __builtin_amdgcn_mfma_f32_16x16x32_f16(a0_, P3, acc[0][3], 0, 0, 0); \
        acc[1][0] = __builtin_amdgcn_mfma_f32_16x16x32_f16(a1_, P0, acc[1][0], 0, 0, 0); \
        acc[1][1] = __builtin_amdgcn_mfma_f32_16x16x32_f16(a1_, P1, acc[1][1], 0, 0, 0); \
        acc[1][2] = __builtin_amdgcn_mfma_f32_16x16x32_f16(a1_, P2, acc[1][2], 0, 0, 0); \
        acc[1][3] = __builtin_amdgcn_mfma_f32_16x16x32_f16(a1_, P3, acc[1][3], 0, 0, 0); \
        acc[2][0] = __builtin_amdgcn_mfma_f32_16x16x32_f16(a2_, P0, acc[2][0], 0, 0, 0); \
        acc[2][1] = __builtin_amdgcn_mfma_f32_16x16x32_f16(a2_, P1, acc[2][1], 0, 0, 0); \
        acc[2][2] = __builtin_amdgcn_mfma_f32_16x16x32_f16(a2_, P2, acc[2][2], 0, 0, 0); \
        acc[2][3] = __builtin_amdgcn_mfma_f32_16x16x32_f16(a2_, P3, acc[2][3], 0, 0, 0); \
        acc[3][0] = __builtin_amdgcn_mfma_f32_16x16x32_f16(a3_, P0, acc[3][0], 0, 0, 0); \
        acc[3][1] = __builtin_amdgcn_mfma_f32_16x16x32_f16(a3_, P1, acc[3][1], 0, 0, 0); \
        acc[3][2] = __builtin_amdgcn_mfma_f32_16x16x32_f16(a3_, P2, acc[3][2], 0, 0, 0); \
        acc[3][3] = __builtin_amdgcn_mfma_f32_16x16x32_f16(a3_, P3, acc[3][3], 0, 0, 0); \
    }

    const int swz = (r16 & 7) << 4;
#pragma unroll
    for (int h = 0; h < HALVES; ++h) {
        if (h > 0) {
            __syncthreads();            // all waves done reading half 0
            stage(A2, nullptr);
            __syncthreads();
            // refill B queue AFTER the restage: no B regs live across it
            LDB(pa0, pa1, pa2, pa3, 8)
            LDB(pb0, pb1, pb2, pb3, 9)
            LDB(pc0, pc1, pc2, pc3, 10)
            LDB(pd0, pd1, pd2, pd3, 11)
        }
        int au = r16 * ROWB + kc * 16;
#pragma unroll
        for (int tt = 0; tt < 8; tt += 4) {
            const int t = h * 8 + tt;   // global K-step for B indexing
            MSTEP((au      ) ^ swz, pa0, pa1, pa2, pa3)
            if (tt + 4 < 8) LDB(pa0, pa1, pa2, pa3, t + 4)
            MSTEP((au +  64) ^ swz, pb0, pb1, pb2, pb3)
            if (tt + 5 < 8) LDB(pb0, pb1, pb2, pb3, t + 5)
            MSTEP((au + 128) ^ swz, pc0, pc1, pc2, pc3)
            if (tt + 6 < 8) LDB(pc0, pc1, pc2, pc3, t + 6)
            MSTEP((au + 192) ^ swz, pd0, pd1, pd2, pd3)
            if (tt + 7 < 8) LDB(pd0, pd1, pd2, pd3, t + 7)
            au += 256;
        }
    }
#undef LDB
#undef MSTEP

    // epilogue: C[m = quad*4+reg][n = lane&15] per 16x16 tile (m89 layout)
    const int rbase = (lane >> 4) * 4;
    const int ncol  = lane & 15;
    if constexpr (BUN == 2) {
        // fp32 LDS C-tile -> per-(row,bundle) Q^T transform -> d_out direct
        __syncthreads();                // all waves done reading Alds
        float* Cl = (float*)Alds;
        constexpr int CS4 = NOUT + 8;
#pragma unroll
        for (int nt = 0; nt < 4; nt++) {
            const int n = wave * 64 + nt * 16 + ncol;
            const float bs = bias[n];
#pragma unroll
            for (int mt = 0; mt < 4; mt++)
#pragma unroll
                for (int i = 0; i < 4; i++)
                    Cl[(mt * 16 + rbase + i) * CS4 + n] = acc[mt][nt][i] + bs;
        }
        __syncthreads();
#pragma unroll
        for (int it = 0; it < 4096 / NOUT; it++) {
            const int item = tid + it * NOUT;
            const int row = item >> 6, b = item & 63;
            float4 v = *(const float4*)&Cl[row * CS4 + b * 4];
            float Q[4][4];
            make_Q(nrq + (size_t)(m0 + row) * 384 + b * 6, Q);
            float4 o;
            o.x = Q[0][0]*v.x + Q[1][0]*v.y + Q[2][0]*v.z + Q[3][0]*v.w;
            o.y = Q[0][1]*v.x + Q[1][1]*v.y + Q[2][1]*v.z + Q[3][1]*v.w;
            o.z = Q[0][2]*v.x + Q[1][2]*v.y + Q[2][2]*v.z + Q[3][2]*v.w;
            o.w = Q[0][3]*v.x + Q[1][3]*v.y + Q[2][3]*v.z + Q[3][3]*v.w;
            *(float4*)(outf + (size_t)(m0 + row) * 256 + b * 4) = o;
        }
    } else {
        // W16: coalesced path via padded fp16 LDS C-tile
        __syncthreads();                // all waves done reading Alds
        constexpr int CPRN = NOUT / 8;  // 16B chunks per C row
        constexpr int CPT  = 64 * CPRN / NOUT;   // chunks per thread (= 8)
        // issue coalesced residual loads early (hide under gelu VALU work)
        f16x8 res[CPT];
        if constexpr (RESA) {
#pragma unroll
            for (int k2 = 0; k2 < CPT; k2++) {
                const int c = tid + k2 * NOUT;
                const int row = c / CPRN, col = c - row * CPRN;
                res[k2] = *(const f16x8*)(A1 + (size_t)(m0 + row) * 256 + col * 8);
            }
        }
        // scatter bias+act into padded LDS C-tile
#pragma unroll
        for (int nt = 0; nt < 4; nt++) {
            const int n = wave * 64 + nt * 16 + ncol;
            const float bs = bias[n];
#pragma unroll
            for (int mt = 0; mt < 4; mt++) {
#pragma unroll
                for (int i = 0; i < 4; i++) {
                    const int mr = mt * 16 + rbase + i;
                    float v = acc[mt][nt][i] + bs;
                    if (ACT) v = gelu_f(v);
                    Alds[mr * CTS + n] = (_Float16)v;
                }
            }
        }
        __syncthreads();
        // coalesced row-write (+ packed fp16 residual add)
#pragma unroll
        for (int k2 = 0; k2 < CPT; k2++) {
            const int c = tid + k2 * NOUT;
            const int row = c / CPRN, col = c - row * CPRN;
            f16x8 v = *(const f16x8*)&Alds[row * CTS + col * 8];
            if constexpr (RESA) v = v + res[k2];
            *(f16x8*)(C16 + (size_t)(m0 + row) * NOUT + col * 8) = v;
        }
        if constexpr (BUN == 1) {
            // fused bundle<false>: vf16[n, b*4+i] = sum_j Q[i][j] x[n, b*4+j]
            constexpr int NIT = (4096 + NOUT - 1) / NOUT;
#pragma unroll
            for (int it = 0; it < NIT; it++) {
                const int item = tid + it * NOUT;
                if (item < 4096) {
                    const int row = item >> 6, b = item & 63;
                    float4 xv = *(const float4*)(xin + (size_t)(m0 + row) * 256 + b * 4);
                    float Q[4][4];
                    make_Q(&Alds[row * CTS + b * 6], Q);
                    f16x4 o = {
                        (_Float16)(Q[0][0]*xv.x + Q[0][1]*xv.y + Q[0][2]*xv.z + Q[0][3]*xv.w),
                        (_Float16)(Q[1][0]*xv.x + Q[1][1]*xv.y + Q[1][2]*xv.z + Q[1][3]*xv.w),
                        (_Float16)(Q[2][0]*xv.x + Q[2][1]*xv.y + Q[2][2]*xv.z + Q[2][3]*xv.w),
                        (_Float16)(Q[3][0]*xv.x + Q[3][1]*xv.y + Q[3][2]*xv.z + Q[3][3]*xv.w) };
                    *(f16x4*)(vf16 + (size_t)(m0 + row) * 256 + b * 4) = o;
                }
            }
        }
    }
}

// ---------------------------------------------------------------------------
// Merged prep kernel: 5 weight packs + bias combine + deg zero in ONE launch.
// ---------------------------------------------------------------------------
__device__ __forceinline__ void pack_body(
    const float* __restrict__ W1, const float* __restrict__ W2,
    _Float16* __restrict__ Bp, int cid, int NOUT, int lognt)
{
    const int NT = 1 << lognt;
    const int l  = cid & 63;
    const int q  = (cid >> 6) & 3;
    const int c2 = cid >> 8;            // wn*NT + t
    const int t  = c2 & (NT - 1);
    const int wn = c2 >> lognt;
    const int n  = wn * 64 + q * 16 + (l & 15);
    const int k0 = t * 32 + (l >> 4) * 8;
    f16x8 v;
#pragma unroll
    for (int j = 0; j < 8; j++) {
        const int k = k0 + j;
        float w = (W2 && k >= 256) ? W2[(size_t)(k - 256) * NOUT + n]
                                   : W1[(size_t)k * NOUT + n];
        v[j] = (_Float16)w;
    }
    *(f16x8*)(Bp + (size_t)cid * 8) = v;
}

__global__ __launch_bounds__(256) void packall_k(
    const float* __restrict__ enc_w, const float* __restrict__ self_w,
    const float* __restrict__ nb_w, const float* __restrict__ dec_w,
    const float* __restrict__ lin_w, const float* __restrict__ self_b,
    const float* __restrict__ nb_b,
    _Float16* __restrict__ enc16, _Float16* __restrict__ l1w,
    _Float16* __restrict__ l2w, _Float16* __restrict__ dec16,
    _Float16* __restrict__ lin16, float* __restrict__ lbias,
    float* __restrict__ degf)
{
    const int b = blockIdx.x;
    const int tid = threadIdx.x;
    if (b < 32) {
        pack_body(enc_w, nullptr, enc16, b * 256 + tid, 256, 3);
    } else if (b < 96) {
        pack_body(self_w, nb_w, l1w, (b - 32) * 256 + tid, 256, 4);
    } else if (b < 160) {
        pack_body(self_w + 65536, nb_w + 65536, l2w, (b - 96) * 256 + tid, 256, 4);
    } else if (b < 208) {
        pack_body(dec_w, nullptr, dec16, (b - 160) * 256 + tid, 384, 3);
    } else if (b < 240) {
        pack_body(lin_w, nullptr, lin16, (b - 208) * 256 + tid, 256, 3);
    } else if (b == 240) {
        for (int i = tid; i < 512; i += 256) lbias[i] = self_b[i] + nb_b[i];
    } else {
        // zero deg: 65536 ints = 16384 float4s
        const int j = (b - 241) * 256 + tid;
        ((float4*)degf)[j] = make_float4(0.f, 0.f, 0.f, 0.f);
    }
}

// ---------------------------------------------------------------------------
// CSR build: histogram of dst, exclusive scan, cursor fill
// ---------------------------------------------------------------------------
__global__ __launch_bounds__(256) void hist_k(const int* __restrict__ ei, int* __restrict__ deg)
{
    int e = blockIdx.x * 256 + threadIdx.x;
    if (e < NEDGE) atomicAdd(&deg[ei[NEDGE + e]], 1);
}

__global__ __launch_bounds__(1024) void scan_k(
    const int* __restrict__ deg, int* __restrict__ off, int* __restrict__ cursor)
{
    __shared__ int sh[1024];
    const int tid = threadIdx.x;
    const int base = tid * 64;
    int s = 0;
#pragma unroll 8
    for (int i = 0; i < 64; i++) s += deg[base + i];
    const int mysum = s;
    sh[tid] = s;
    __syncthreads();
    for (int ofs = 1; ofs < 1024; ofs <<= 1) {
        int v = (tid >= ofs) ? sh[tid - ofs] : 0;
        __syncthreads();
        sh[tid] += v;
        __syncthreads();
    }
    int running = sh[tid] - mysum;
    for (int i = 0; i < 64; i++) {
        off[base + i] = running;
        cursor[base + i] = running;
        running += deg[base + i];
    }
    if (tid == 1023) off[NN] = running;
}

__global__ __launch_bounds__(256) void fill_k(
    const int* __restrict__ ei, int* __restrict__ cursor, int* __restrict__ csr)
{
    int e = blockIdx.x * 256 + threadIdx.x;
    if (e < NEDGE) {
        int d = ei[NEDGE + e];
        int pos = atomicAdd(&cursor[d], 1);
        csr[pos] = ei[e];   // src
    }
}

// ---------------------------------------------------------------------------
// Gather segment-sum over fp16 h: fp32 accum, fp16 out. 8 rows in flight.
// ---------------------------------------------------------------------------
__global__ __launch_bounds__(256) void gather16_k(
    const _Float16* __restrict__ h, const int* __restrict__ off,
    const int* __restrict__ csr, _Float16* __restrict__ agg)
{
    const int lane = threadIdx.x & 63;
    const int n = blockIdx.x * 4 + (threadIdx.x >> 6);
    const int s0 = off[n], s1 = off[n + 1];
    float a0 = 0.f, a1 = 0.f, a2 = 0.f, a3 = 0.f;
    int j = s0;
    for (; j + 7 < s1; j += 8) {
        const int i0 = csr[j],     i1 = csr[j + 1], i2 = csr[j + 2], i3 = csr[j + 3];
        const int i4 = csr[j + 4], i5 = csr[j + 5], i6 = csr[j + 6], i7 = csr[j + 7];
        f16x4 v0 = ((const f16x4*)(h + (size_t)i0 * CH))[lane];
        f16x4 v1 = ((const f16x4*)(h + (size_t)i1 * CH))[lane];
        f16x4 v2 = ((const f16x4*)(h + (size_t)i2 * CH))[lane];
        f16x4 v3 = ((const f16x4*)(h + (size_t)i3 * CH))[lane];
        f16x4 v4 = ((const f16x4*)(h + (size_t)i4 * CH))[lane];
        f16x4 v5 = ((const f16x4*)(h + (size_t)i5 * CH))[lane];
        f16x4 v6 = ((const f16x4*)(h + (size_t)i6 * CH))[lane];
        f16x4 v7 = ((const f16x4*)(h + (size_t)i7 * CH))[lane];
        a0 += ((float)v0[0] + (float)v1[0]) + ((float)v2[0] + (float)v3[0])
            + ((float)v4[0] + (float)v5[0]) + ((float)v6[0] + (float)v7[0]);
        a1 += ((float)v0[1] + (float)v1[1]) + ((float)v2[1] + (float)v3[1])
            + ((float)v4[1] + (float)v5[1]) + ((float)v6[1] + (float)v7[1]);
        a2 += ((float)v0[2] + (float)v1[2]) + ((float)v2[2] + (float)v3[2])
            + ((float)v4[2] + (float)v5[2]) + ((float)v6[2] + (float)v7[2]);
        a3 += ((float)v0[3] + (float)v1[3]) + ((float)v2[3] + (float)v3[3])
            + ((float)v4[3] + (float)v5[3]) + ((float)v6[3] + (float)v7[3]);
    }
    for (; j + 1 < s1; j += 2) {
        const int i0 = csr[j], i1 = csr[j + 1];
        f16x4 v0 = ((const f16x4*)(h + (size_t)i0 * CH))[lane];
        f16x4 v1 = ((const f16x4*)(h + (size_t)i1 * CH))[lane];
        a0 += (float)v0[0] + (float)v1[0]; a1 += (float)v0[1] + (float)v1[1];
        a2 += (float)v0[2] + (float)v1[2]; a3 += (float)v0[3] + (float)v1[3];
    }
    if (j < s1) {
        f16x4 va = ((const f16x4*)(h + (size_t)csr[j] * CH))[lane];
        a0 += (float)va[0]; a1 += (float)va[1]; a2 += (float)va[2]; a3 += (float)va[3];
    }
    f16x4 o = { (_Float16)a0, (_Float16)a1, (_Float16)a2, (_Float16)a3 };
    ((f16x4*)(agg + (size_t)n * CH))[lane] = o;
}

// ---------------------------------------------------------------------------
// Spectral kernels (vf is fp16). spec_proj: atomic-free private partials;
// hsum: 8-way reduce (16 MB -> 2 MB); spec_reproj: reads reduced hs.
// ---------------------------------------------------------------------------
__global__ __launch_bounds__(256) void spec_proj_k(
    const _Float16* __restrict__ v, const float* __restrict__ eigvec,
    float* __restrict__ hs8)
{
    const int g = blockIdx.x;
    const int yb = blockIdx.y;
    const int nbase = g * NPG + yb * 128;
    __shared__ float evs[16][32];
    float acc[32];
#pragma unroll
    for (int k = 0; k < 32; k++) acc[k] = 0.f;
    for (int nt = 0; nt < 128; nt += 16) {
        __syncthreads();
        for (int i = threadIdx.x; i < 512; i += 256) {
            int nn = i >> 5, kk = i & 31;
            evs[nn][kk] = eigvec[(size_t)(nbase + nt + nn) * KEIG + kk];
        }
        __syncthreads();
#pragma unroll 4
        for (int nn = 0; nn < 16; nn++) {
            float hv = (float)v[(size_t)(nbase + nt + nn) * CH + threadIdx.x];
#pragma unroll
            for (int k = 0; k < 32; k++) acc[k] += evs[nn][k] * hv;
        }
    }
    float* o = hs8 + (((size_t)g * 8 + yb) * KEIG) * CH + threadIdx.x;
#pragma unroll
    for (int k = 0; k < 32; k++) o[k * CH] = acc[k];
}

__global__ __launch_bounds__(256) void hsum_k(
    const float* __restrict__ hs8, float* __restrict__ hs)
{
    const size_t i = (size_t)blockIdx.x * 256 + threadIdx.x;  // over 64*32*256
    const int g = (int)(i >> 13);            // i / 8192
    const size_t r = i & 8191;
    const float* p = hs8 + (size_t)g * 8 * 8192 + r;
    float s = ((p[0] + p[8192]) + (p[2 * 8192] + p[3 * 8192]))
            + ((p[4 * 8192] + p[5 * 8192]) + (p[6 * 8192] + p[7 * 8192]));
    hs[i] = s;
}

// out16[g,n,d] = sum_v ev[g,n,v] * hs[g,v,d] * exp(-eigval[g,v]*taus[d>>2])
__global__ __launch_bounds__(256) void spec_reproj16_k(
    const float* __restrict__ eigvec, const float* __restrict__ hs,
    const float* __restrict__ eigval, const float* __restrict__ taus,
    _Float16* __restrict__ out16)
{
    const int g = blockIdx.x >> 4;
    const int nbase = g * NPG + (blockIdx.x & 15) * 64;
    const float tau = taus[threadIdx.x >> 2];
    float hsr[32];
    const float* hg = hs + (size_t)g * KEIG * CH + threadIdx.x;
#pragma unroll
    for (int k = 0; k < 32; k++)
        hsr[k] = hg[k * CH] * expf(-eigval[g * KEIG + k] * tau);
    __shared__ float evs[64][32];
    for (int i = threadIdx.x; i < 2048; i += 256) {
        int nn = i >> 5, kk = i & 31;
        evs[nn][kk] = eigvec[(size_t)(nbase + nn) * KEIG + kk];
    }
    __syncthreads();
    for (int nn = 0; nn < 64; nn++) {
        float a = 0.f;
#pragma unroll
        for (int k = 0; k < 32; k++) a += evs[nn][k] * hsr[k];
        out16[(size_t)(nbase + nn) * CH + threadIdx.x] = (_Float16)a;
    }
}

// ---------------------------------------------------------------------------
extern "C" void kernel_launch(void* const* d_in, const int* in_sizes, int n_in,
                              void* d_out, int out_size, void* d_ws, size_t ws_size,
                              hipStream_t stream)
{
    const float* x      = (const float*)d_in[0];
    const float* eigvec = (const float*)d_in[1];
    const float* eigval = (const float*)d_in[2];
    const float* taus   = (const float*)d_in[3];
    const float* enc_w  = (const float*)d_in[4];
    const float* enc_b  = (const float*)d_in[5];
    const float* self_w = (const float*)d_in[6];
    const float* self_b = (const float*)d_in[7];
    const float* nb_w   = (const float*)d_in[8];
    const float* nb_b   = (const float*)d_in[9];
    const float* dec_w  = (const float*)d_in[10];
    const float* dec_b  = (const float*)d_in[11];
    const float* lin_w  = (const float*)d_in[12];
    const float* lin_b  = (const float*)d_in[13];
    const int*   ei     = (const int*)d_in[14];
    (void)in_sizes; (void)n_in; (void)out_size; (void)ws_size;

    float* ws = (float*)d_ws;
    // Stream-ordered lifetimes (float-slot offsets):
    //  [0,        4194304)  hs8 [64,8,32,256] fp32 partials (16 MB)
    //  [4194304,  4718592)  hs  [64,32,256] fp32 reduced (2 MB)
    //  [8388608, 16777216)  h0
    //  [16777216,25165824)  h1 -> vf16 [NN,256] fp16 (h1 dead after L2)
    //  [25165824,33554432)  agg          -> nr16 part
    //  [33554432,34275329)  CSR ints     -> nr16 part
    //  [25165824,37748736)  nr16 [NN,384] fp16 (dec out; agg+CSR dead)
    //  [37748752,37995024)  packed weights + lbias
    //  [37995024,46383632)  h2 [NN,256] fp16
    // high-water: 46,383,632 fl = 185.5 MB
    _Float16* h0  = (_Float16*)(ws + 8388608);
    _Float16* h1  = (_Float16*)(ws + 16777216);
    _Float16* agg = (_Float16*)(ws + 25165824);
    int* ibase  = (int*)(ws + 33554432);
    int* deg    = ibase;                 // NN
    int* off    = ibase + 65536;         // NN+1
    int* cursor = ibase + 131073;        // NN
    int* csr    = ibase + 196609;        // NEDGE (ends slot 34275329)
    _Float16* nr16 = (_Float16*)(ws + 25165824);  // [NN,384] fp16
    float* wb = ws + 37748752;
    _Float16* enc16 = (_Float16*)(wb);            // packed [256x256]
    _Float16* l1w   = (_Float16*)(wb + 32768);    // packed [256x512]
    _Float16* l2w   = (_Float16*)(wb + 98304);    // packed [256x512]
    _Float16* dec16 = (_Float16*)(wb + 163840);   // packed [384x256]
    _Float16* lin16 = (_Float16*)(wb + 212992);   // packed [256x256]
    float* lbias = wb + 245760;                   // [2,256] (ends wb+246272)
    _Float16* h2 = (_Float16*)(ws + 37995024);    // [NN,256] fp16
    _Float16* vf16 = (_Float16*)(ws + 16777216);  // [NN,256] fp16 (h1 dead)
    float* hs8 = ws;                              // [64,8,32,256] fp32
    float* hs  = ws + 4194304;                    // [64,32,256] fp32

    dim3 blk(256);

    // ---- prep: packs + bias + deg zero in ONE launch ----
    packall_k<<<305, blk, 0, stream>>>(enc_w, self_w, nb_w, dec_w, lin_w,
        self_b, nb_b, enc16, l1w, l2w, dec16, lin16, lbias, (float*)deg);
    hist_k<<<NEDGE / 256, blk, 0, stream>>>(ei, deg);
    scan_k<<<1, 1024, 0, stream>>>(deg, off, cursor);
    fill_k<<<NEDGE / 256, blk, 0, stream>>>(ei, cursor, csr);

    // ---- h0 = gelu(x @ enc_w + enc_b)  (A32: stages fp32 x directly) ----
    mgemm_k<256, 256, false, true, false, true, true, 0><<<1024, blk, 0, stream>>>(
        nullptr, nullptr, x, enc16, enc_b, h0, nullptr, nullptr, nullptr, nullptr);

    // ---- GNN layer 1: h1 = gelu([h0,agg]@W + b) + h0 ----
    gather16_k<<<NN / 4, blk, 0, stream>>>(h0, off, csr, agg);
    mgemm_k<256, 512, true, true, true, true, false, 0><<<1024, blk, 0, stream>>>(
        h0, agg, nullptr, l1w, lbias, h1, nullptr, nullptr, nullptr, nullptr);

    // ---- GNN layer 2: h0 = gelu([h1,agg]@W + b) + h1 ----
    gather16_k<<<NN / 4, blk, 0, stream>>>(h1, off, csr, agg);
    mgemm_k<256, 512, true, true, true, true, false, 0><<<1024, blk, 0, stream>>>(
        h1, agg, nullptr, l2w, lbias + 256, h0, nullptr, nullptr, nullptr, nullptr);

    // ---- node_rep = h0 @ dec_w + dec_b  + FUSED vf16 = Q . x ----
    mgemm_k<384, 256, false, false, false, true, false, 1><<<1024, dim3(384), 0, stream>>>(
        h0, nullptr, nullptr, dec16, dec_b, nr16, x, vf16, nullptr, nullptr);

    // ---- spectral filter (atomic-free partials + tiny reduce) ----
    spec_proj_k<<<dim3(GG, 8), blk, 0, stream>>>(vf16, eigvec, hs8);
    hsum_k<<<2048, blk, 0, stream>>>(hs8, hs);
    spec_reproj16_k<<<GG * 16, blk, 0, stream>>>(eigvec, hs, eigval, taus, h2);

    // ---- out = Q^T . (h2 @ lin_w + lin_b)  (FUSED, fp32 tile, direct) ----
    mgemm_k<256, 256, false, false, false, false, false, 2><<<1024, blk, 0, stream>>>(
        h2, nullptr, nullptr, lin16, lin_b, nullptr, nullptr, nullptr, nr16, (float*)d_out);
}